// Round 13
// baseline (135.294 us; speedup 1.0000x reference)
//
#include <hip/hip_runtime.h>

#define NN 100000
#define NE 1600000
#define NW 25000          // NN/4 packed-byte words
#define NWH 12500         // words per node-range half (50KB LDS)
#define NWH4 3125         // NWH/4 uint4
#define S_D 64            // dst-histogram slices
#define S_S 64            // src-histogram slices
#define EPS (NE / S_D)    // 25000 edges per slice
#define AGG_GRID 2048     // persistent blocks for k_agg1 (8 per CU)
#define REPLAY_NB ((NE + 255) / 256)    // 6250 blocks for the replay half
#define PROJ_NB   ((NN / 16 + 3) / 4)   // 1563 blocks for the proj half

typedef unsigned int uint;
typedef _Float16 f16x8 __attribute__((ext_vector_type(8)));
typedef _Float16 f16x2 __attribute__((ext_vector_type(2)));
typedef float f32x4 __attribute__((ext_vector_type(4)));

// ---------------- packed-byte LDS histogram, 50KB blocks ----------------
// grid (S_D, 4): y = (key<<1)|range. key 0 = dst (records rank), 1 = src.
// Each block histograms its edge slice for nodes in [range*50000, +50000).
__global__ void __launch_bounds__(256)
k_hist(const int* __restrict__ src, const int* __restrict__ dst,
       uint* __restrict__ partial_in, uint* __restrict__ partial_out,
       unsigned char* __restrict__ lr) {
    __shared__ uint4 cnt4[NWH4];          // 50,000 B packed byte counters
    uint* cnt = (uint*)cnt4;
    int sl = blockIdx.x;
    int is_src = blockIdx.y >> 1;
    uint wbase = (blockIdx.y & 1) * NWH;
    for (int w = threadIdx.x; w < NWH4; w += 256) cnt4[w] = make_uint4(0, 0, 0, 0);
    __syncthreads();
    int base = sl * EPS;
    if (!is_src) {
        for (int i4 = threadIdx.x; i4 < EPS / 4; i4 += 256) {
            int e = base + i4 * 4;
            int4 k4 = *(const int4*)&dst[e];
            {
                uint rw = (uint)(k4.x >> 2) - wbase;
                if (rw < NWH) {
                    uint sh = (uint)(k4.x & 3) * 8u;
                    uint old = atomicAdd(&cnt[rw], 1u << sh);
                    lr[e] = (unsigned char)((old >> sh) & 0xffu);
                }
            }
            {
                uint rw = (uint)(k4.y >> 2) - wbase;
                if (rw < NWH) {
                    uint sh = (uint)(k4.y & 3) * 8u;
                    uint old = atomicAdd(&cnt[rw], 1u << sh);
                    lr[e + 1] = (unsigned char)((old >> sh) & 0xffu);
                }
            }
            {
                uint rw = (uint)(k4.z >> 2) - wbase;
                if (rw < NWH) {
                    uint sh = (uint)(k4.z & 3) * 8u;
                    uint old = atomicAdd(&cnt[rw], 1u << sh);
                    lr[e + 2] = (unsigned char)((old >> sh) & 0xffu);
                }
            }
            {
                uint rw = (uint)(k4.w >> 2) - wbase;
                if (rw < NWH) {
                    uint sh = (uint)(k4.w & 3) * 8u;
                    uint old = atomicAdd(&cnt[rw], 1u << sh);
                    lr[e + 3] = (unsigned char)((old >> sh) & 0xffu);
                }
            }
        }
        __syncthreads();
        uint4* dp = (uint4*)(partial_in + (size_t)sl * NW + wbase);
        for (int w = threadIdx.x; w < NWH4; w += 256) dp[w] = cnt4[w];
    } else {
        for (int i4 = threadIdx.x; i4 < EPS / 4; i4 += 256) {
            int e = base + i4 * 4;
            int4 k4 = *(const int4*)&src[e];
            {
                uint rw = (uint)(k4.x >> 2) - wbase;
                if (rw < NWH) atomicAdd(&cnt[rw], 1u << ((uint)(k4.x & 3) * 8u));
            }
            {
                uint rw = (uint)(k4.y >> 2) - wbase;
                if (rw < NWH) atomicAdd(&cnt[rw], 1u << ((uint)(k4.y & 3) * 8u));
            }
            {
                uint rw = (uint)(k4.z >> 2) - wbase;
                if (rw < NWH) atomicAdd(&cnt[rw], 1u << ((uint)(k4.z & 3) * 8u));
            }
            {
                uint rw = (uint)(k4.w >> 2) - wbase;
                if (rw < NWH) atomicAdd(&cnt[rw], 1u << ((uint)(k4.w & 3) * 8u));
            }
        }
        __syncthreads();
        uint4* dp = (uint4*)(partial_out + (size_t)sl * NW + wbase);
        for (int w = threadIdx.x; w < NWH4; w += 256) dp[w] = cnt4[w];
    }
}

// ---------------- fused: byte-prefix + norms + exclusive node scan (parallel lookback) ----------------
// look[] must be zeroed before launch. Each block publishes its own sum (+1);
// wave 0 polls all predecessors lane-parallel — no serial chain.
__global__ void __launch_bounds__(256)
k_degscan(uint* __restrict__ partial_in, const uint* __restrict__ partial_out,
          float* __restrict__ norm_in, float* __restrict__ norm_out,
          int* __restrict__ row_ofs, int* __restrict__ look, int nb) {
    __shared__ int red[4];
    __shared__ int s_excl;
    int t = threadIdx.x;
    int w = blockIdx.x * 256 + t;
    int d0 = 0, d1 = 0, d2 = 0, d3 = 0;
    if (w < NW) {
        uint run = 0;
#pragma unroll 8
        for (int s = 0; s < S_D; ++s) {
            uint u = partial_in[(size_t)s * NW + w];
            partial_in[(size_t)s * NW + w] = run;
            run += u;
        }
        uint ro = 0;
#pragma unroll 8
        for (int s = 0; s < S_S; ++s) ro += partial_out[(size_t)s * NW + w];
        d0 = run & 0xff; d1 = (run >> 8) & 0xff; d2 = (run >> 16) & 0xff; d3 = (run >> 24) & 0xff;
        float4 fi, fo;
        fi.x = d0 > 0 ? rsqrtf((float)d0) : 1.0f;
        fi.y = d1 > 0 ? rsqrtf((float)d1) : 1.0f;
        fi.z = d2 > 0 ? rsqrtf((float)d2) : 1.0f;
        fi.w = d3 > 0 ? rsqrtf((float)d3) : 1.0f;
        int o0 = ro & 0xff, o1 = (ro >> 8) & 0xff, o2 = (ro >> 16) & 0xff, o3 = (ro >> 24) & 0xff;
        fo.x = o0 > 0 ? rsqrtf((float)o0) : 1.0f;
        fo.y = o1 > 0 ? rsqrtf((float)o1) : 1.0f;
        fo.z = o2 > 0 ? rsqrtf((float)o2) : 1.0f;
        fo.w = o3 > 0 ? rsqrtf((float)o3) : 1.0f;
        *(float4*)&norm_in[w * 4]  = fi;
        *(float4*)&norm_out[w * 4] = fo;
    }
    int loc = d0 + d1 + d2 + d3;
    int v = loc;
    int lane = t & 63;
#pragma unroll
    for (int off = 1; off < 64; off <<= 1) {
        int u = __shfl_up(v, off, 64);
        if (lane >= off) v += u;
    }
    if (lane == 63) red[t >> 6] = v;
    __syncthreads();
    if (t < 64) {
        if (t == 0) {   // publish own block sum (+1 sentinel)
            int total = red[0] + red[1] + red[2] + red[3];
            __hip_atomic_store(&look[blockIdx.x], total + 1,
                               __ATOMIC_RELEASE, __HIP_MEMORY_SCOPE_AGENT);
        }
        int sum = 0;
        for (int i = t; i < blockIdx.x; i += 64) {   // poll predecessors, lane-parallel
            int vv;
            do {
                vv = __hip_atomic_load(&look[i], __ATOMIC_ACQUIRE, __HIP_MEMORY_SCOPE_AGENT);
            } while (vv == 0);
            sum += vv - 1;
        }
#pragma unroll
        for (int off = 32; off; off >>= 1) sum += __shfl_xor(sum, off, 64);
        if (t == 0) s_excl = sum;
    }
    __syncthreads();
    int wv = t >> 6;
    int wbase2 = 0;
    if (wv > 0) wbase2 += red[0];
    if (wv > 1) wbase2 += red[1];
    if (wv > 2) wbase2 += red[2];
    int excl = s_excl + wbase2 + (v - loc);
    if (w < NW) {
        int n = w * 4;
        row_ofs[n] = excl;     excl += d0;
        row_ofs[n + 1] = excl; excl += d1;
        row_ofs[n + 2] = excl; excl += d2;
        row_ofs[n + 3] = excl;
    }
    if (blockIdx.x == nb - 1 && t == 0)
        row_ofs[NN] = s_excl + red[0] + red[1] + red[2] + red[3];   // == NE
}

// ---------------- merged: atomic-free CSR fill ∥ MFMA projection ----------------
__global__ void __launch_bounds__(256)
k_repl_proj(const int* __restrict__ src, const int* __restrict__ dst,
            const uint* __restrict__ base_bytes, const unsigned char* __restrict__ lr,
            const int* __restrict__ row_ofs, int* __restrict__ csr_src,
            const float* __restrict__ x, const float* __restrict__ norm_out,
            const float* __restrict__ W1, _Float16* __restrict__ y) {
    if (blockIdx.x < REPLAY_NB) {
        int e = blockIdx.x * 256 + threadIdx.x;
        if (e < NE) {
            int d  = dst[e];
            int sl = e / EPS;
            uint pw = base_bytes[(size_t)sl * NW + (d >> 2)];
            int b = (int)((pw >> ((d & 3) * 8)) & 0xffu);
            csr_src[row_ofs[d] + b + (int)lr[e]] = src[e];
        }
        return;
    }
    // ---- proj half ----
    int lane = threadIdx.x & 63;
    int col  = lane & 15;
    int kh   = lane >> 4;
    f16x8 wf[4][2];
#pragma unroll
    for (int t = 0; t < 4; ++t)
#pragma unroll
        for (int s = 0; s < 2; ++s)
#pragma unroll
            for (int j = 0; j < 8; ++j)
                wf[t][s][j] = (_Float16)W1[(s * 32 + kh * 8 + j) * 64 + t * 16 + col];
    int tile = (blockIdx.x - REPLAY_NB) * 4 + (threadIdx.x >> 6);
    if (tile >= NN / 16) return;
    int base = tile * 16;
    int row  = base + col;
    float no = norm_out[row];
    const float* xr = &x[(size_t)row * 64 + kh * 8];
    f16x8 af[2];
#pragma unroll
    for (int s = 0; s < 2; ++s) {
        float4 v0 = *(const float4*)&xr[s * 32];
        float4 v1 = *(const float4*)&xr[s * 32 + 4];
        af[s][0] = (_Float16)(v0.x * no); af[s][1] = (_Float16)(v0.y * no);
        af[s][2] = (_Float16)(v0.z * no); af[s][3] = (_Float16)(v0.w * no);
        af[s][4] = (_Float16)(v1.x * no); af[s][5] = (_Float16)(v1.y * no);
        af[s][6] = (_Float16)(v1.z * no); af[s][7] = (_Float16)(v1.w * no);
    }
    f32x4 acc[4];
#pragma unroll
    for (int t = 0; t < 4; ++t) acc[t] = (f32x4){0.f, 0.f, 0.f, 0.f};
#pragma unroll
    for (int t = 0; t < 4; ++t) {
        acc[t] = __builtin_amdgcn_mfma_f32_16x16x32_f16(af[0], wf[t][0], acc[t], 0, 0, 0);
        acc[t] = __builtin_amdgcn_mfma_f32_16x16x32_f16(af[1], wf[t][1], acc[t], 0, 0, 0);
    }
#pragma unroll
    for (int t = 0; t < 4; ++t)
#pragma unroll
        for (int r = 0; r < 4; ++r)
            y[(size_t)(base + kh * 4 + r) * 64 + t * 16 + col] = (_Float16)acc[t][r];
}

// ---------------- aggregate y (f16 gather) + relu/W2 epilogue ----------------
__device__ inline float2 up2(uint u) {
    f16x2 p = __builtin_bit_cast(f16x2, u);
    return make_float2((float)p.x, (float)p.y);
}

__global__ void __launch_bounds__(256)
k_agg1(const int* __restrict__ csr_src, const int* __restrict__ row_ofs,
       const uint* __restrict__ xb, const float* __restrict__ norm_in,
       const float* __restrict__ norm_out,
       const float* __restrict__ b1, const float* __restrict__ W2,
       float* __restrict__ z) {
    int tid = threadIdx.x;
    int lane = tid & 63, q = lane >> 4, lq = lane & 15;
    float4 bb = *(const float4*)&b1[lq * 4];
    float4 ww = *(const float4*)&W2[lq * 4];
    const size_t lqo = (size_t)(lq << 3);
    for (int n = blockIdx.x * 4 + (tid >> 6); n < NN; n += AGG_GRID * 4) {
        int beg = row_ofs[n], end = row_ofs[n + 1];
        float a0 = 0, a1 = 0, a2 = 0, a3 = 0;
        int ei = beg + q;
        for (; ei + 12 < end; ei += 16) {     // 16 edges in flight per wave
            int s0 = csr_src[ei], s1 = csr_src[ei + 4];
            int s2 = csr_src[ei + 8], s3 = csr_src[ei + 12];
            uint2 u0 = *(const uint2*)((const char*)xb + ((size_t)s0 << 7) + lqo);
            uint2 u1 = *(const uint2*)((const char*)xb + ((size_t)s1 << 7) + lqo);
            uint2 u2 = *(const uint2*)((const char*)xb + ((size_t)s2 << 7) + lqo);
            uint2 u3 = *(const uint2*)((const char*)xb + ((size_t)s3 << 7) + lqo);
            float2 p0 = up2(u0.x), r0 = up2(u0.y);
            float2 p1 = up2(u1.x), r1 = up2(u1.y);
            float2 p2 = up2(u2.x), r2 = up2(u2.y);
            float2 p3 = up2(u3.x), r3 = up2(u3.y);
            a0 += (p0.x + p1.x) + (p2.x + p3.x);
            a1 += (p0.y + p1.y) + (p2.y + p3.y);
            a2 += (r0.x + r1.x) + (r2.x + r3.x);
            a3 += (r0.y + r1.y) + (r2.y + r3.y);
        }
        for (; ei < end; ei += 4) {           // <=3 tail edges per quarter
            int s0 = csr_src[ei];
            uint2 u0 = *(const uint2*)((const char*)xb + ((size_t)s0 << 7) + lqo);
            float2 p0 = up2(u0.x), r0 = up2(u0.y);
            a0 += p0.x; a1 += p0.y; a2 += r0.x; a3 += r0.y;
        }
        a0 += __shfl_xor(a0, 16, 64); a0 += __shfl_xor(a0, 32, 64);
        a1 += __shfl_xor(a1, 16, 64); a1 += __shfl_xor(a1, 32, 64);
        a2 += __shfl_xor(a2, 16, 64); a2 += __shfl_xor(a2, 32, 64);
        a3 += __shfl_xor(a3, 16, 64); a3 += __shfl_xor(a3, 32, 64);
        float nin = norm_in[n];
        float h0 = fmaxf(a0 * nin + bb.x, 0.0f);
        float h1 = fmaxf(a1 * nin + bb.y, 0.0f);
        float h2 = fmaxf(a2 * nin + bb.z, 0.0f);
        float h3 = fmaxf(a3 * nin + bb.w, 0.0f);
        float zv = h0 * ww.x + h1 * ww.y + h2 * ww.z + h3 * ww.w;
#pragma unroll
        for (int off = 8; off; off >>= 1) zv += __shfl_xor(zv, off, 64);
        if (lane == 0) z[n] = zv * norm_out[n];
    }
}

// ---------------- layer 2 gather + sigmoid ----------------
__global__ void k_out2(const int* __restrict__ csr_src, const int* __restrict__ row_ofs,
                       const float* __restrict__ z, const float* __restrict__ norm_in,
                       const float* __restrict__ b2, float* __restrict__ out) {
    int n = blockIdx.x * blockDim.x + threadIdx.x;
    if (n < NN) {
        int beg = row_ofs[n], end = row_ofs[n + 1];
        float a = 0.0f;
        int i = beg;
        for (; i + 3 < end; i += 4) {
            float z0 = z[csr_src[i]], z1 = z[csr_src[i + 1]];
            float z2 = z[csr_src[i + 2]], z3 = z[csr_src[i + 3]];
            a += (z0 + z1) + (z2 + z3);
        }
        for (; i < end; ++i) a += z[csr_src[i]];
        float v = a * norm_in[n] + b2[0];
        out[n] = 1.0f / (1.0f + expf(-v));
    }
}

// ---------------- launch ----------------

extern "C" void kernel_launch(void* const* d_in, const int* in_sizes, int n_in,
                              void* d_out, int out_size, void* d_ws, size_t ws_size,
                              hipStream_t stream) {
    const float* x   = (const float*)d_in[0];
    const int*   src = (const int*)d_in[1];
    const int*   dst = (const int*)d_in[2];
    const float* W1  = (const float*)d_in[3];
    const float* b1  = (const float*)d_in[4];
    const float* W2  = (const float*)d_in[5];
    const float* b2  = (const float*)d_in[6];
    float* out = (float*)d_out;

    // ws layout (4B words):
    //   [0, 0.4M)       lr                     live: hist -> repl_proj
    //   [0.4M, 2.0M)    partial_in (S_D*NW)    live: hist -> repl_proj (read by replay half)
    //   [2.0M, 3.6M)    csr_src                written by repl_proj, live to end
    //   [3.6M, 5.2M)    partial_out (S_S*NW)   dead after k_degscan
    //   [3.6M, 6.8M)    xb (aliases partial_out + fresh; written by proj half)
    //   [6.8M, ~7.2M)   row_ofs, norms, z, look
    uint* W0 = (uint*)d_ws;
    unsigned char* lr          = (unsigned char*)W0;                  // 400K words
    uint*          partial_in  = W0 + 400000;                         // 1.6M words
    int*           csr_src     = (int*)(W0 + 2000000);                // 1.6M words
    uint*          partial_out = W0 + 3600000;                        // 1.6M words
    uint*          xb          = W0 + 3600000;                        // 3.2M words (phase B)
    int*           row_ofs     = (int*)(W0 + 6800000);                // NN+1
    float*         norm_in     = (float*)(row_ofs + NN + 32);         // NN
    float*         norm_out    = norm_in + NN;                        // NN
    float*         z           = norm_out + NN;                       // NN
    int*           look        = (int*)(z + NN);                      // 128

    int nb = (NN + 1023) / 1024;   // 98

    hipMemsetAsync(look, 0, 512, stream);
    k_hist     <<<dim3(S_D, 4), 256, 0, stream>>>(src, dst, partial_in, partial_out, lr);
    k_degscan  <<<nb, 256, 0, stream>>>(partial_in, partial_out, norm_in, norm_out,
                                        row_ofs, look, nb);
    k_repl_proj<<<REPLAY_NB + PROJ_NB, 256, 0, stream>>>(src, dst, partial_in, lr,
                                                         row_ofs, csr_src, x, norm_out,
                                                         W1, (_Float16*)xb);
    k_agg1     <<<AGG_GRID, 256, 0, stream>>>(csr_src, row_ofs, xb, norm_in, norm_out,
                                              b1, W2, z);
    k_out2     <<<(NN + 255) / 256, 256, 0, stream>>>(csr_src, row_ofs, z, norm_in, b2, out);
}

// Round 14
// 126.281 us; speedup vs baseline: 1.0714x; 1.0714x over previous
//
#include <hip/hip_runtime.h>

#define NN 100000
#define NE 1600000
#define NW 25000          // NN/4 packed-byte words
#define NW4 6250          // NW/4 uint4 words
#define S_D 64            // dst-histogram slices
#define EPS_D (NE / S_D)  // 25000 edges per dst slice
#define S_S 64            // src-histogram slices
#define EPS_S (NE / S_S)  // 25000 edges per src slice
#define AGG_GRID 2048     // persistent blocks for k_agg1 (8 per CU)
#define REPLAY_NB ((NE + 255) / 256)    // 6250 blocks for the replay half
#define PROJ_NB   ((NN / 16 + 3) / 4)   // 1563 blocks for the proj half

typedef unsigned int uint;
typedef _Float16 f16x8 __attribute__((ext_vector_type(8)));
typedef _Float16 f16x2 __attribute__((ext_vector_type(2)));
typedef float f32x4 __attribute__((ext_vector_type(4)));

// ---------------- packed-byte LDS histogram over ALL nodes (100KB LDS) ----------------
// grid (S_D, 2): y=0 counts dst (records local rank), y=1 counts src
__global__ void __launch_bounds__(256)
k_hist(const int* __restrict__ src, const int* __restrict__ dst,
       uint* __restrict__ partial_in, uint* __restrict__ partial_out,
       unsigned char* __restrict__ lr) {
    __shared__ uint4 cnt4[NW4];          // 100,000 B packed byte counters
    uint* cnt = (uint*)cnt4;
    int sl = blockIdx.x;
    int y  = blockIdx.y;
    for (int w = threadIdx.x; w < NW4; w += 256) cnt4[w] = make_uint4(0, 0, 0, 0);
    __syncthreads();
    if (y == 0) {
        int base = sl * EPS_D;
        for (int i4 = threadIdx.x; i4 < EPS_D / 4; i4 += 256) {
            int e = base + i4 * 4;
            int4 k4 = *(const int4*)&dst[e];
            uint sh0 = (uint)(k4.x & 3) * 8u, sh1 = (uint)(k4.y & 3) * 8u;
            uint sh2 = (uint)(k4.z & 3) * 8u, sh3 = (uint)(k4.w & 3) * 8u;
            uint r0 = (atomicAdd(&cnt[k4.x >> 2], 1u << sh0) >> sh0) & 0xffu;
            uint r1 = (atomicAdd(&cnt[k4.y >> 2], 1u << sh1) >> sh1) & 0xffu;
            uint r2 = (atomicAdd(&cnt[k4.z >> 2], 1u << sh2) >> sh2) & 0xffu;
            uint r3 = (atomicAdd(&cnt[k4.w >> 2], 1u << sh3) >> sh3) & 0xffu;
            uchar4 pk = make_uchar4((unsigned char)r0, (unsigned char)r1,
                                    (unsigned char)r2, (unsigned char)r3);
            *(uchar4*)&lr[e] = pk;
        }
        __syncthreads();
        uint4* dp = (uint4*)(partial_in + (size_t)sl * NW);
        for (int w = threadIdx.x; w < NW4; w += 256) dp[w] = cnt4[w];
    } else {
        int base = sl * EPS_S;
        for (int i4 = threadIdx.x; i4 < EPS_S / 4; i4 += 256) {
            int e = base + i4 * 4;
            int4 k4 = *(const int4*)&src[e];
            atomicAdd(&cnt[k4.x >> 2], 1u << ((uint)(k4.x & 3) * 8u));
            atomicAdd(&cnt[k4.y >> 2], 1u << ((uint)(k4.y & 3) * 8u));
            atomicAdd(&cnt[k4.z >> 2], 1u << ((uint)(k4.z & 3) * 8u));
            atomicAdd(&cnt[k4.w >> 2], 1u << ((uint)(k4.w & 3) * 8u));
        }
        __syncthreads();
        uint4* dp = (uint4*)(partial_out + (size_t)sl * NW);
        for (int w = threadIdx.x; w < NW4; w += 256) dp[w] = cnt4[w];
    }
}

// ---------------- byte-SIMD prefix over slices + degrees + norms + block sums ----------------
__global__ void k_degnorm(uint* __restrict__ partial_in, const uint* __restrict__ partial_out,
                          int* __restrict__ deg_in, float* __restrict__ norm_in,
                          float* __restrict__ norm_out, int* __restrict__ bsum) {
    __shared__ int red[4];
    int w = blockIdx.x * 256 + threadIdx.x;
    int mysum = 0;
    if (w < NW) {
        uint run = 0;
#pragma unroll 8
        for (int s = 0; s < S_D; ++s) {
            uint u = partial_in[(size_t)s * NW + w];
            partial_in[(size_t)s * NW + w] = run;
            run += u;
        }
        uint ro = 0;
#pragma unroll 8
        for (int s = 0; s < S_S; ++s) ro += partial_out[(size_t)s * NW + w];
        int4 dg;
        float4 fi, fo;
        int d0 = run & 0xff, d1 = (run >> 8) & 0xff, d2 = (run >> 16) & 0xff, d3 = (run >> 24) & 0xff;
        dg = make_int4(d0, d1, d2, d3);
        fi.x = d0 > 0 ? rsqrtf((float)d0) : 1.0f;
        fi.y = d1 > 0 ? rsqrtf((float)d1) : 1.0f;
        fi.z = d2 > 0 ? rsqrtf((float)d2) : 1.0f;
        fi.w = d3 > 0 ? rsqrtf((float)d3) : 1.0f;
        int o0 = ro & 0xff, o1 = (ro >> 8) & 0xff, o2 = (ro >> 16) & 0xff, o3 = (ro >> 24) & 0xff;
        fo.x = o0 > 0 ? rsqrtf((float)o0) : 1.0f;
        fo.y = o1 > 0 ? rsqrtf((float)o1) : 1.0f;
        fo.z = o2 > 0 ? rsqrtf((float)o2) : 1.0f;
        fo.w = o3 > 0 ? rsqrtf((float)o3) : 1.0f;
        *(int4*)&deg_in[w * 4]     = dg;
        *(float4*)&norm_in[w * 4]  = fi;
        *(float4*)&norm_out[w * 4] = fo;
        mysum = d0 + d1 + d2 + d3;
    }
#pragma unroll
    for (int off = 32; off; off >>= 1) mysum += __shfl_xor(mysum, off, 64);
    if ((threadIdx.x & 63) == 0) red[threadIdx.x >> 6] = mysum;
    __syncthreads();
    if (threadIdx.x == 0) bsum[blockIdx.x] = red[0] + red[1] + red[2] + red[3];
}

// ---------------- exclusive scan of deg_in; block prefix computed redundantly per block ----------------
__global__ void k_scan(const int* __restrict__ deg_in, const int* __restrict__ bsum,
                       int* __restrict__ row_ofs, int nb) {
    __shared__ int wofs[4];
    __shared__ int sbofs;
    int t = threadIdx.x;
    if (t < 64) {            // wave 0: redundant wave-scan of bsum -> this block's offset
        int lane = t;
        int v0 = (lane * 2     < nb) ? bsum[lane * 2]     : 0;
        int v1 = (lane * 2 + 1 < nb) ? bsum[lane * 2 + 1] : 0;
        int pair = v0 + v1;
        int pre = pair;
#pragma unroll
        for (int off = 1; off < 64; off <<= 1) {
            int u = __shfl_up(pre, off, 64);
            if (lane >= off) pre += u;
        }
        int basep = pre - pair;                  // exclusive prefix of pair `lane`
        int bx = blockIdx.x;
        int b   = __shfl(basep, bx >> 1, 64);
        int v0b = __shfl(v0,    bx >> 1, 64);
        if (lane == 0) sbofs = (bx & 1) ? b + v0b : b;
        if (blockIdx.x == 0 && lane == 63) row_ofs[NN] = pre;   // total == NE
    }
    int base = blockIdx.x * 1024 + t * 4;
    int d[4];
#pragma unroll
    for (int k = 0; k < 4; ++k) {
        int n = base + k;
        d[k] = (n < NN) ? deg_in[n] : 0;
    }
    int loc = d[0] + d[1] + d[2] + d[3];
    int v = loc;
    int lane = t & 63;
#pragma unroll
    for (int off = 1; off < 64; off <<= 1) {
        int u = __shfl_up(v, off, 64);
        if (lane >= off) v += u;
    }
    if (lane == 63) wofs[t >> 6] = v;
    __syncthreads();
    int w = t >> 6;
    int wbase = 0;
    if (w > 0) wbase += wofs[0];
    if (w > 1) wbase += wofs[1];
    if (w > 2) wbase += wofs[2];
    int excl = sbofs + wbase + (v - loc);
#pragma unroll
    for (int k = 0; k < 4; ++k) {
        int n = base + k;
        if (n < NN) { row_ofs[n] = excl; excl += d[k]; }
    }
}

// ---------------- merged: atomic-free CSR fill ∥ MFMA projection ----------------
// blocks [0, REPLAY_NB): csr_src[row_ofs[dst]+base+lr] = src   (reads partial_in, lr)
// blocks [REPLAY_NB, REPLAY_NB+PROJ_NB): y = f16((x .* norm_out) @ W1) into xb
__global__ void __launch_bounds__(256)
k_repl_proj(const int* __restrict__ src, const int* __restrict__ dst,
            const uint* __restrict__ base_bytes, const unsigned char* __restrict__ lr,
            const int* __restrict__ row_ofs, int* __restrict__ csr_src,
            const float* __restrict__ x, const float* __restrict__ norm_out,
            const float* __restrict__ W1, _Float16* __restrict__ y) {
    if (blockIdx.x < REPLAY_NB) {
        int e = blockIdx.x * 256 + threadIdx.x;
        if (e < NE) {
            int d  = dst[e];
            int sl = e / EPS_D;
            uint pw = base_bytes[(size_t)sl * NW + (d >> 2)];
            int b = (int)((pw >> ((d & 3) * 8)) & 0xffu);
            csr_src[row_ofs[d] + b + (int)lr[e]] = src[e];
        }
        return;
    }
    // ---- proj half ----
    int lane = threadIdx.x & 63;
    int col  = lane & 15;
    int kh   = lane >> 4;
    f16x8 wf[4][2];
#pragma unroll
    for (int t = 0; t < 4; ++t)
#pragma unroll
        for (int s = 0; s < 2; ++s)
#pragma unroll
            for (int j = 0; j < 8; ++j)
                wf[t][s][j] = (_Float16)W1[(s * 32 + kh * 8 + j) * 64 + t * 16 + col];
    int tile = (blockIdx.x - REPLAY_NB) * 4 + (threadIdx.x >> 6);
    if (tile >= NN / 16) return;
    int base = tile * 16;
    int row  = base + col;
    float no = norm_out[row];
    const float* xr = &x[(size_t)row * 64 + kh * 8];
    f16x8 af[2];
#pragma unroll
    for (int s = 0; s < 2; ++s) {
        float4 v0 = *(const float4*)&xr[s * 32];
        float4 v1 = *(const float4*)&xr[s * 32 + 4];
        af[s][0] = (_Float16)(v0.x * no); af[s][1] = (_Float16)(v0.y * no);
        af[s][2] = (_Float16)(v0.z * no); af[s][3] = (_Float16)(v0.w * no);
        af[s][4] = (_Float16)(v1.x * no); af[s][5] = (_Float16)(v1.y * no);
        af[s][6] = (_Float16)(v1.z * no); af[s][7] = (_Float16)(v1.w * no);
    }
    f32x4 acc[4];
#pragma unroll
    for (int t = 0; t < 4; ++t) acc[t] = (f32x4){0.f, 0.f, 0.f, 0.f};
#pragma unroll
    for (int t = 0; t < 4; ++t) {
        acc[t] = __builtin_amdgcn_mfma_f32_16x16x32_f16(af[0], wf[t][0], acc[t], 0, 0, 0);
        acc[t] = __builtin_amdgcn_mfma_f32_16x16x32_f16(af[1], wf[t][1], acc[t], 0, 0, 0);
    }
#pragma unroll
    for (int t = 0; t < 4; ++t)
#pragma unroll
        for (int r = 0; r < 4; ++r)
            y[(size_t)(base + kh * 4 + r) * 64 + t * 16 + col] = (_Float16)acc[t][r];
}

// ---------------- aggregate y (f16 gather) + relu/W2 epilogue ----------------
__device__ inline float2 up2(uint u) {
    f16x2 p = __builtin_bit_cast(f16x2, u);
    return make_float2((float)p.x, (float)p.y);
}

__global__ void __launch_bounds__(256)
k_agg1(const int* __restrict__ csr_src, const int* __restrict__ row_ofs,
       const uint* __restrict__ xb, const float* __restrict__ norm_in,
       const float* __restrict__ norm_out,
       const float* __restrict__ b1, const float* __restrict__ W2,
       float* __restrict__ z) {
    int tid = threadIdx.x;
    int lane = tid & 63, q = lane >> 4, lq = lane & 15;
    float4 bb = *(const float4*)&b1[lq * 4];
    float4 ww = *(const float4*)&W2[lq * 4];
    const size_t lqo = (size_t)(lq << 3);
    for (int n = blockIdx.x * 4 + (tid >> 6); n < NN; n += AGG_GRID * 4) {
        int beg = row_ofs[n], end = row_ofs[n + 1];
        float a0 = 0, a1 = 0, a2 = 0, a3 = 0;
        int ei = beg + q;
        for (; ei + 12 < end; ei += 16) {     // 16 edges in flight per wave
            int s0 = csr_src[ei], s1 = csr_src[ei + 4];
            int s2 = csr_src[ei + 8], s3 = csr_src[ei + 12];
            uint2 u0 = *(const uint2*)((const char*)xb + ((size_t)s0 << 7) + lqo);
            uint2 u1 = *(const uint2*)((const char*)xb + ((size_t)s1 << 7) + lqo);
            uint2 u2 = *(const uint2*)((const char*)xb + ((size_t)s2 << 7) + lqo);
            uint2 u3 = *(const uint2*)((const char*)xb + ((size_t)s3 << 7) + lqo);
            float2 p0 = up2(u0.x), r0 = up2(u0.y);
            float2 p1 = up2(u1.x), r1 = up2(u1.y);
            float2 p2 = up2(u2.x), r2 = up2(u2.y);
            float2 p3 = up2(u3.x), r3 = up2(u3.y);
            a0 += (p0.x + p1.x) + (p2.x + p3.x);
            a1 += (p0.y + p1.y) + (p2.y + p3.y);
            a2 += (r0.x + r1.x) + (r2.x + r3.x);
            a3 += (r0.y + r1.y) + (r2.y + r3.y);
        }
        for (; ei < end; ei += 4) {           // <=3 tail edges per quarter
            int s0 = csr_src[ei];
            uint2 u0 = *(const uint2*)((const char*)xb + ((size_t)s0 << 7) + lqo);
            float2 p0 = up2(u0.x), r0 = up2(u0.y);
            a0 += p0.x; a1 += p0.y; a2 += r0.x; a3 += r0.y;
        }
        a0 += __shfl_xor(a0, 16, 64); a0 += __shfl_xor(a0, 32, 64);
        a1 += __shfl_xor(a1, 16, 64); a1 += __shfl_xor(a1, 32, 64);
        a2 += __shfl_xor(a2, 16, 64); a2 += __shfl_xor(a2, 32, 64);
        a3 += __shfl_xor(a3, 16, 64); a3 += __shfl_xor(a3, 32, 64);
        float nin = norm_in[n];
        float h0 = fmaxf(a0 * nin + bb.x, 0.0f);
        float h1 = fmaxf(a1 * nin + bb.y, 0.0f);
        float h2 = fmaxf(a2 * nin + bb.z, 0.0f);
        float h3 = fmaxf(a3 * nin + bb.w, 0.0f);
        float zv = h0 * ww.x + h1 * ww.y + h2 * ww.z + h3 * ww.w;
#pragma unroll
        for (int off = 8; off; off >>= 1) zv += __shfl_xor(zv, off, 64);
        if (lane == 0) z[n] = zv * norm_out[n];
    }
}

// ---------------- layer 2 gather + sigmoid ----------------
__global__ void k_out2(const int* __restrict__ csr_src, const int* __restrict__ row_ofs,
                       const float* __restrict__ z, const float* __restrict__ norm_in,
                       const float* __restrict__ b2, float* __restrict__ out) {
    int n = blockIdx.x * blockDim.x + threadIdx.x;
    if (n < NN) {
        int beg = row_ofs[n], end = row_ofs[n + 1];
        float a = 0.0f;
        int i = beg;
        for (; i + 3 < end; i += 4) {
            float z0 = z[csr_src[i]], z1 = z[csr_src[i + 1]];
            float z2 = z[csr_src[i + 2]], z3 = z[csr_src[i + 3]];
            a += (z0 + z1) + (z2 + z3);
        }
        for (; i < end; ++i) a += z[csr_src[i]];
        float v = a * norm_in[n] + b2[0];
        out[n] = 1.0f / (1.0f + expf(-v));
    }
}

// ---------------- launch ----------------

extern "C" void kernel_launch(void* const* d_in, const int* in_sizes, int n_in,
                              void* d_out, int out_size, void* d_ws, size_t ws_size,
                              hipStream_t stream) {
    const float* x   = (const float*)d_in[0];
    const int*   src = (const int*)d_in[1];
    const int*   dst = (const int*)d_in[2];
    const float* W1  = (const float*)d_in[3];
    const float* b1  = (const float*)d_in[4];
    const float* W2  = (const float*)d_in[5];
    const float* b2  = (const float*)d_in[6];
    float* out = (float*)d_out;

    // ws layout (4B words):
    //   [0, 0.4M)       lr                     live: hist -> repl_proj
    //   [0.4M, 2.0M)    partial_in (S_D*NW)    live: hist -> repl_proj (read by replay half)
    //   [2.0M, 3.6M)    csr_src                written by repl_proj, live to end
    //   [3.6M, 5.2M)    partial_out (S_S*NW)   dead after k_degnorm
    //   [3.6M, 6.8M)    xb (aliases partial_out + fresh; written by proj half)
    //   [6.8M, ~7.3M)   row_ofs, deg_in, norms, z, bsum      (peak ~29.2 MB)
    uint* W0 = (uint*)d_ws;
    unsigned char* lr          = (unsigned char*)W0;                  // 400K words
    uint*          partial_in  = W0 + 400000;                         // 1.6M words
    int*           csr_src     = (int*)(W0 + 2000000);                // 1.6M words
    uint*          partial_out = W0 + 3600000;                        // 1.6M words
    uint*          xb          = W0 + 3600000;                        // 3.2M words (phase B)
    int*           row_ofs     = (int*)(W0 + 6800000);                // NN+1
    int*           deg_in      = row_ofs + NN + 32;                   // NN
    float*         norm_in     = (float*)(deg_in + NN);               // NN
    float*         norm_out    = norm_in + NN;                        // NN
    float*         z           = norm_out + NN;                       // NN
    int*           bsum        = (int*)(z + NN);                      // 98

    int nb = (NN + 1023) / 1024;   // 98

    k_hist     <<<dim3(S_D, 2), 256, 0, stream>>>(src, dst, partial_in, partial_out, lr);
    k_degnorm  <<<nb, 256, 0, stream>>>(partial_in, partial_out, deg_in, norm_in,
                                        norm_out, bsum);
    k_scan     <<<nb, 256, 0, stream>>>(deg_in, bsum, row_ofs, nb);
    k_repl_proj<<<REPLAY_NB + PROJ_NB, 256, 0, stream>>>(src, dst, partial_in, lr,
                                                         row_ofs, csr_src, x, norm_out,
                                                         W1, (_Float16*)xb);
    k_agg1     <<<AGG_GRID, 256, 0, stream>>>(csr_src, row_ofs, xb, norm_in, norm_out,
                                              b1, W2, z);
    k_out2     <<<(NN + 255) / 256, 256, 0, stream>>>(csr_src, row_ofs, z, norm_in, b2, out);
}